// Round 2
// baseline (259.963 us; speedup 1.0000x reference)
//
#include <hip/hip_runtime.h>

// ScaledDotProductAttention: B=4,H=8,S=2048,Dh=64, fp32 in/out, key-padding mask.
// Flash attention, bf16 MFMA 16x16x32, fp32 accum. 4 waves/block, 16 q-rows/wave.

#define S_LEN 2048
#define DH 64
#define SCALE 0.04419417382415922f   // 1/sqrt(512)  (d_model, not d_head)
#define LOG2E 1.4426950408889634f

typedef __attribute__((ext_vector_type(8))) short bf16x8;
typedef __attribute__((ext_vector_type(4))) float f32x4;

__device__ __forceinline__ short f2bf(float f) {
    unsigned u = __float_as_uint(f);
    u += 0x7FFF + ((u >> 16) & 1);   // RNE
    return (short)(u >> 16);
}

// XOR swizzle: 16B blocks within a 128B row, keyed by row&7 (G4 fix)
#define SW(r, e) ((e) ^ (((r) & 7) << 3))

__global__ __launch_bounds__(256, 2)
void attn_fwd(const float* __restrict__ Qg, const float* __restrict__ Kg,
              const float* __restrict__ Vg, const int* __restrict__ lens,
              float* __restrict__ Og)
{
    __shared__ short Klds[64][64];     // K tile, row-major [key][d], swizzled
    __shared__ short Vt[64][64];       // V tile transposed [d][key], swizzled
    __shared__ short Plds[4][16][64];  // per-wave P [q][key], swizzled

    const int tid  = threadIdx.x;
    const int wave = tid >> 6;
    const int lane = tid & 63;
    const int lr   = lane & 15;   // 0..15
    const int lg   = lane >> 4;   // 0..3

    const int bh = blockIdx.y;                 // b*H + h
    const int L  = lens[bh >> 3];              // H = 8
    const int q0 = blockIdx.x * 64 + wave * 16;

    const size_t base = (size_t)bh * S_LEN * DH;

    // ---- Q fragments (A-layout: row = lane%16, k = 8*(lane/16)+j), scaled ----
    bf16x8 qf[2];
    {
        const float* qrow = Qg + base + (size_t)(q0 + lr) * DH + 8 * lg;
        #pragma unroll
        for (int ks = 0; ks < 2; ++ks) {
            float4 a = *(const float4*)(qrow + 32 * ks);
            float4 b = *(const float4*)(qrow + 32 * ks + 4);
            bf16x8 f;
            f[0] = f2bf(a.x * SCALE); f[1] = f2bf(a.y * SCALE);
            f[2] = f2bf(a.z * SCALE); f[3] = f2bf(a.w * SCALE);
            f[4] = f2bf(b.x * SCALE); f[5] = f2bf(b.y * SCALE);
            f[6] = f2bf(b.z * SCALE); f[7] = f2bf(b.w * SCALE);
            qf[ks] = f;
        }
    }

    f32x4 Of[4];
    #pragma unroll
    for (int n = 0; n < 4; ++n) Of[n] = (f32x4){0.f, 0.f, 0.f, 0.f};
    float m_run[4], d_run[4];
    #pragma unroll
    for (int r = 0; r < 4; ++r) { m_run[r] = -1e30f; d_run[r] = 0.f; }

    const int ntiles = (L + 63) >> 6;   // skip fully-masked key tiles (exact)

    for (int t = 0; t < ntiles; ++t) {
        const int kb = t * 64;
        __syncthreads();   // previous tile's LDS reads done before overwrite

        // ---- stage K tile: float4 loads, short4 swizzled LDS writes ----
        {
            const float4* kt = (const float4*)(Kg + base + (size_t)kb * DH);
            int row = tid >> 4;
            const int c4 = tid & 15;
            #pragma unroll
            for (int it = 0; it < 4; ++it, row += 16) {
                float4 v = kt[row * 16 + c4];
                short4 s;
                s.x = f2bf(v.x); s.y = f2bf(v.y);
                s.z = f2bf(v.z); s.w = f2bf(v.w);
                *(short4*)&Klds[row][SW(row, c4 * 4)] = s;
            }
        }
        // ---- stage V transposed: scalar loads (coalesced per 8-lane group),
        //      key-rotated so swizzled scalar writes are ~2-way ----
        {
            const float* vt = Vg + base + (size_t)kb * DH;
            #pragma unroll
            for (int i = 0; i < 16; ++i) {
                int key = wave * 16 + ((i + (lane >> 3)) & 15);
                Vt[lane][SW(lane, key)] = f2bf(vt[key * DH + lane]);
            }
        }
        __syncthreads();

        // ---- S = (Q*SCALE) K^T ----
        f32x4 Sv[4];
        #pragma unroll
        for (int n = 0; n < 4; ++n) Sv[n] = (f32x4){0.f, 0.f, 0.f, 0.f};
        #pragma unroll
        for (int ks = 0; ks < 2; ++ks) {
            #pragma unroll
            for (int n = 0; n < 4; ++n) {
                bf16x8 kf = *(const bf16x8*)&Klds[16 * n + lr][SW(16 * n + lr, 8 * lg + 32 * ks)];
                Sv[n] = __builtin_amdgcn_mfma_f32_16x16x32_bf16(qf[ks], kf, Sv[n], 0, 0, 0);
            }
        }

        // ---- boundary mask (key col = 16n + lane%16) ----
        if (kb + 64 > L) {
            #pragma unroll
            for (int n = 0; n < 4; ++n)
                if (kb + 16 * n + lr >= L) {
                    Sv[n][0] = -1e30f; Sv[n][1] = -1e30f;
                    Sv[n][2] = -1e30f; Sv[n][3] = -1e30f;
                }
        }

        // ---- online softmax; row q = 4*lg + r, cols spread over lanes 0..15 ----
        #pragma unroll
        for (int r = 0; r < 4; ++r) {
            float mx = fmaxf(fmaxf(Sv[0][r], Sv[1][r]), fmaxf(Sv[2][r], Sv[3][r]));
            mx = fmaxf(mx, __shfl_xor(mx, 1, 64));
            mx = fmaxf(mx, __shfl_xor(mx, 2, 64));
            mx = fmaxf(mx, __shfl_xor(mx, 4, 64));
            mx = fmaxf(mx, __shfl_xor(mx, 8, 64));
            float mnew = fmaxf(m_run[r], mx);
            float corr = exp2f((m_run[r] - mnew) * LOG2E);
            m_run[r] = mnew;
            float rs = 0.f;
            #pragma unroll
            for (int n = 0; n < 4; ++n) {
                float p = exp2f((Sv[n][r] - mnew) * LOG2E);
                Sv[n][r] = p;
                rs += p;
            }
            rs += __shfl_xor(rs, 1, 64);
            rs += __shfl_xor(rs, 2, 64);
            rs += __shfl_xor(rs, 4, 64);
            rs += __shfl_xor(rs, 8, 64);
            d_run[r] = d_run[r] * corr + rs;
            #pragma unroll
            for (int n = 0; n < 4; ++n) Of[n][r] *= corr;
        }

        // ---- P -> LDS (D-layout scatter), then read back as A-fragments ----
        #pragma unroll
        for (int r = 0; r < 4; ++r) {
            int q = 4 * lg + r;
            #pragma unroll
            for (int n = 0; n < 4; ++n)
                Plds[wave][q][SW(q, 16 * n + lr)] = f2bf(Sv[n][r]);
        }

        // ---- O += P V  (A = P rows q, B = V^T-staged so col = d) ----
        #pragma unroll
        for (int ks = 0; ks < 2; ++ks) {
            bf16x8 pf = *(const bf16x8*)&Plds[wave][lr][SW(lr, 8 * lg + 32 * ks)];
            #pragma unroll
            for (int n = 0; n < 4; ++n) {
                bf16x8 vf = *(const bf16x8*)&Vt[16 * n + lr][SW(16 * n + lr, 8 * lg + 32 * ks)];
                Of[n] = __builtin_amdgcn_mfma_f32_16x16x32_bf16(pf, vf, Of[n], 0, 0, 0);
            }
        }
    }

    // ---- epilogue: O / denom -> global (D-layout scatter, coalesced per group) ----
    float inv[4];
    #pragma unroll
    for (int r = 0; r < 4; ++r) inv[r] = 1.f / d_run[r];
    float* orow = Og + base + (size_t)q0 * DH;
    #pragma unroll
    for (int r = 0; r < 4; ++r) {
        int q = 4 * lg + r;
        #pragma unroll
        for (int n = 0; n < 4; ++n)
            orow[(size_t)q * DH + 16 * n + lr] = Of[n][r] * inv[r];
    }
}

extern "C" void kernel_launch(void* const* d_in, const int* in_sizes, int n_in,
                              void* d_out, int out_size, void* d_ws, size_t ws_size,
                              hipStream_t stream) {
    const float* Q = (const float*)d_in[0];
    const float* K = (const float*)d_in[1];
    const float* V = (const float*)d_in[2];
    const int* lens = (const int*)d_in[3];
    float* O = (float*)d_out;
    dim3 grid(S_LEN / 64, 4 * 8);
    attn_fwd<<<grid, 256, 0, stream>>>(Q, K, V, lens, O);
}